// Round 13
// baseline (39.673 us; speedup 1.0000x reference)
//
#include <hip/hip_runtime.h>

#define NGUESS 256
#define NCHUNK 1000

// AES inverse S-box: INV_SBOX[SBOX[x]] == x
__device__ __constant__ int INV_SBOXD[256] = {
   82,   9, 106, 213,  48,  54, 165,  56, 191,  64, 163, 158, 129, 243, 215, 251,
  124, 227,  57, 130, 155,  47, 255, 135,  52, 142,  67,  68, 196, 222, 233, 203,
   84, 123, 148,  50, 166, 194,  35,  61, 238,  76, 149,  11,  66, 250, 195,  78,
    8,  46, 161, 102,  40, 217,  36, 178, 118,  91, 162,  73, 109, 139, 209,  37,
  114, 248, 246, 100, 134, 104, 152,  22, 212, 164,  92, 204,  93, 101, 182, 146,
  108, 112,  72,  80, 253, 237, 185, 218,  94,  21,  70,  87, 167, 141, 157, 132,
  144, 216, 171,   0, 140, 188, 211,  10, 247, 228,  88,   5, 184, 179,  69,   6,
  208,  44,  30, 143, 202,  63,  15,   2, 193, 175, 189,   3,   1,  19, 138, 107,
   58, 145,  17,  65,  79, 103, 220, 234, 151, 242, 207, 206, 240, 180, 230, 115,
  150, 172, 116,  34, 231, 173,  53, 133, 226, 249,  55, 232,  28, 117, 223, 110,
   71, 241,  26, 113,  29,  41, 197, 137, 111, 183,  98,  14, 170,  24, 190,  27,
  252,  86,  62,  75, 198, 210, 121,  32, 154, 219, 192, 254, 120, 205,  90, 244,
   31, 221, 168,  51, 136,   7, 199,  49, 177,  18,  16,  89,  39, 128, 236,  95,
   96,  81, 127, 169,  25, 181,  74,  13,  45, 229, 122, 159, 147, 201, 156, 239,
  160, 224,  59,  77, 174,  42, 245, 176, 200, 235, 187,  60, 131,  83, 153,  97,
   23,  43,   4, 126, 186, 119, 214,  38, 225, 105,  20,  99,  85,  33,  12, 125
};

// K1: r8's proven kernel (r9 measured ~16.1us = HBM floor). One block per
// 100x256 chunk; wave w owns rows [25w,25w+25); paired-chain scatter(log at
// inv_sbox) / gather(m^l XOR-indexed, conflict-free). Block 0 additionally
// zeroes outRanks (atomics accumulate into it in dispatch 2; harness does
// not re-poison between replays) and writes outX.
__global__ __launch_bounds__(256) void k_chunksums(const float* __restrict__ pred,
                                                   const int* __restrict__ meta,
                                                   float* __restrict__ cs,
                                                   int* __restrict__ outRanks,
                                                   int* __restrict__ outX) {
  __shared__ float prow[4][4][NGUESS];  // [wave][slot][256] 16 KB
  __shared__ float red[4][NGUESS];      // 4 KB

  const int tid = threadIdx.x;
  const int w = tid >> 6;
  const int l = tid & 63;
  const size_t base = (size_t)blockIdx.x * 100 + (size_t)w * 25;

  if (blockIdx.x == 0) {
#pragma unroll
    for (int k = 0; k < 4; ++k) {
      const int c = (tid << 2) + k;
      if (c < NCHUNK) {
        outRanks[c] = 0;
        outX[c] = (c + 1) * 100;
      }
    }
  }

  const int c0 = l << 2;
  const int t0 = INV_SBOXD[c0 + 0];
  const int t1 = INV_SBOXD[c0 + 1];
  const int t2 = INV_SBOXD[c0 + 2];
  const int t3 = INV_SBOXD[c0 + 3];

  const float* rp = pred + (base << 8) + c0;

  auto scat = [&](float* s, const float4& v) {
    s[t0] = __logf(v.x);
    s[t1] = __logf(v.y);
    s[t2] = __logf(v.z);
    s[t3] = __logf(v.w);
  };

  float s0 = 0.f, s1 = 0.f, s2 = 0.f, s3 = 0.f;
  auto gath = [&](const float* ps, int m) {
    const int mx = m ^ l;
    s0 += ps[mx];
    s1 += ps[mx ^ 64];
    s2 += ps[mx ^ 128];
    s3 += ps[mx ^ 192];
  };

  float4 vA = *reinterpret_cast<const float4*>(rp + 0 * NGUESS);
  float4 vB = *reinterpret_cast<const float4*>(rp + 1 * NGUESS);
  float4 nA = *reinterpret_cast<const float4*>(rp + 2 * NGUESS);
  float4 nB = *reinterpret_cast<const float4*>(rp + 3 * NGUESS);
  int pmA = meta[base + 0];
  int pmB = meta[base + 1];

  scat(prow[w][0], vA);
  scat(prow[w][1], vB);

#pragma unroll
  for (int p = 1; p < 12; ++p) {
    vA = nA; vB = nB;
    const int rA = (2 * p + 2 <= 24) ? (2 * p + 2) : 24;
    const int rB = (2 * p + 3 <= 24) ? (2 * p + 3) : 24;
    nA = *reinterpret_cast<const float4*>(rp + (size_t)rA * NGUESS);
    nB = *reinterpret_cast<const float4*>(rp + (size_t)rB * NGUESS);
    const int mA = meta[base + 2 * p];
    const int mB = meta[base + 2 * p + 1];

    float* sA = prow[w][2 * (p & 1)];
    scat(sA, vA);
    scat(sA + NGUESS, vB);

    const float* gA = prow[w][2 * ((p & 1) ^ 1)];
    gath(gA, pmA);
    gath(gA + NGUESS, pmB);

    pmA = mA; pmB = mB;
  }

  scat(prow[w][0], nA);
  gath(prow[w][2], pmA);
  gath(prow[w][3], pmB);
  gath(prow[w][0], meta[base + 24]);

  red[w][l]       = s0;
  red[w][l + 64]  = s1;
  red[w][l + 128] = s2;
  red[w][l + 192] = s3;
  __syncthreads();
  cs[((size_t)blockIdx.x) * NGUESS + tid] =
      red[0][tid] + red[1][tid] + red[2][tid] + red[3][tid];
}

// K2 (fused scan+rank, single dispatch): 256 blocks, one per guess column g.
// Thread t owns chunks [4t, 4t+4). Loads its column AND the key column ck
// (every block redundantly scans ck -> identical doubles -> consistent
// comparisons), one 512-double Hillis-Steele scans both columns in the same
// 8 steps, then predicated global atomicAdd(&outRanks[c],1) where
// S_g[c] > S_ck[c]. Int atomics are order-independent -> deterministic.
__global__ __launch_bounds__(256) void k_scanrank(const float* __restrict__ cs,
                                                  const int* __restrict__ ckp,
                                                  int* __restrict__ outRanks,
                                                  int nc) {
  const int g = blockIdx.x;
  const int t = threadIdx.x;
  const int ck = *ckp;
  const int r0 = t << 2;

  double xg[4], xk[4];
#pragma unroll
  for (int k = 0; k < 4; ++k) {
    const bool in = (r0 + k) < nc;
    xg[k] = in ? (double)cs[(size_t)(r0 + k) * NGUESS + g]  : 0.0;
    xk[k] = in ? (double)cs[(size_t)(r0 + k) * NGUESS + ck] : 0.0;
  }
  // local inclusive prefixes
  double pg[4], pk[4];
  pg[0] = xg[0]; pk[0] = xk[0];
#pragma unroll
  for (int k = 1; k < 4; ++k) { pg[k] = pg[k - 1] + xg[k]; pk[k] = pk[k - 1] + xk[k]; }

  __shared__ double sc[512];
  sc[t] = pg[3];
  sc[256 + t] = pk[3];
  __syncthreads();
#pragma unroll
  for (int off = 1; off < 256; off <<= 1) {
    const double vg = sc[t];
    const double vk = sc[256 + t];
    const double ug = (t >= off) ? sc[t - off] : 0.0;
    const double uk = (t >= off) ? sc[256 + t - off] : 0.0;
    __syncthreads();
    sc[t] = vg + ug;
    sc[256 + t] = vk + uk;
    __syncthreads();
  }
  const double Eg = (t > 0) ? sc[t - 1] : 0.0;
  const double Ek = (t > 0) ? sc[256 + t - 1] : 0.0;

#pragma unroll
  for (int k = 0; k < 4; ++k) {
    const int c = r0 + k;
    if (c < nc && (Eg + pg[k]) > (Ek + pk[k]))
      atomicAdd(&outRanks[c], 1);
  }
}

extern "C" void kernel_launch(void* const* d_in, const int* in_sizes, int n_in,
                              void* d_out, int out_size, void* d_ws, size_t ws_size,
                              hipStream_t stream) {
  const float* pred = (const float*)d_in[0];
  const int* meta   = (const int*)d_in[1];
  // d_in[2] = guess_range (256), d_in[3] = correct_key (34), d_in[4] = step (100)
  const int* ckp    = (const int*)d_in[3];

  const int N = in_sizes[1];             // 100000
  const int num_chunks = N / 100;        // 1000

  float* cs = (float*)d_ws;              // [1000][256] f32

  int* outRanks = (int*)d_out;           // ranks[0..nc)
  int* outX     = outRanks + num_chunks; // x_rank[nc..2nc)

  k_chunksums<<<num_chunks, 256, 0, stream>>>(pred, meta, cs, outRanks, outX);
  k_scanrank <<<NGUESS,     256, 0, stream>>>(cs, ckp, outRanks, num_chunks);
}

// Round 14
// 31.899 us; speedup vs baseline: 1.2437x; 1.2437x over previous
//
#include <hip/hip_runtime.h>

#define NGUESS 256
#define NCHUNK 1000

// AES inverse S-box: INV_SBOX[SBOX[x]] == x
__device__ __constant__ int INV_SBOXD[256] = {
   82,   9, 106, 213,  48,  54, 165,  56, 191,  64, 163, 158, 129, 243, 215, 251,
  124, 227,  57, 130, 155,  47, 255, 135,  52, 142,  67,  68, 196, 222, 233, 203,
   84, 123, 148,  50, 166, 194,  35,  61, 238,  76, 149,  11,  66, 250, 195,  78,
    8,  46, 161, 102,  40, 217,  36, 178, 118,  91, 162,  73, 109, 139, 209,  37,
  114, 248, 246, 100, 134, 104, 152,  22, 212, 164,  92, 204,  93, 101, 182, 146,
  108, 112,  72,  80, 253, 237, 185, 218,  94,  21,  70,  87, 167, 141, 157, 132,
  144, 216, 171,   0, 140, 188, 211,  10, 247, 228,  88,   5, 184, 179,  69,   6,
  208,  44,  30, 143, 202,  63,  15,   2, 193, 175, 189,   3,   1,  19, 138, 107,
   58, 145,  17,  65,  79, 103, 220, 234, 151, 242, 207, 206, 240, 180, 230, 115,
  150, 172, 116,  34, 231, 173,  53, 133, 226, 249,  55, 232,  28, 117, 223, 110,
   71, 241,  26, 113,  29,  41, 197, 137, 111, 183,  98,  14, 170,  24, 190,  27,
  252,  86,  62,  75, 198, 210, 121,  32, 154, 219, 192, 254, 120, 205,  90, 244,
   31, 221, 168,  51, 136,   7, 199,  49, 177,  18,  16,  89,  39, 128, 236,  95,
   96,  81, 127, 169,  25, 181,  74,  13,  45, 229, 122, 159, 147, 201, 156, 239,
  160, 224,  59,  77, 174,  42, 245, 176, 200, 235, 187,  60, 131,  83, 153,  97,
   23,  43,   4, 126, 186, 119, 214,  38, 225, 105,  20,  99,  85,  33,  12, 125
};

// K1: r8's proven kernel (r9 measured ~16.1us = HBM floor: 102.4MB @ 6.36
// TB/s). One block per 100x256 chunk; wave w owns rows [25w,25w+25);
// paired-chain scatter(log at inv_sbox) / gather(m^l XOR-indexed,
// conflict-free: bank=(m^l)&31, 2 lanes/bank).
__global__ __launch_bounds__(256) void k_chunksums(const float* __restrict__ pred,
                                                   const int* __restrict__ meta,
                                                   float* __restrict__ cs) {
  __shared__ float prow[4][4][NGUESS];  // [wave][slot][256] 16 KB
  __shared__ float red[4][NGUESS];      // 4 KB

  const int tid = threadIdx.x;
  const int w = tid >> 6;
  const int l = tid & 63;
  const size_t base = (size_t)blockIdx.x * 100 + (size_t)w * 25;

  const int c0 = l << 2;
  const int t0 = INV_SBOXD[c0 + 0];
  const int t1 = INV_SBOXD[c0 + 1];
  const int t2 = INV_SBOXD[c0 + 2];
  const int t3 = INV_SBOXD[c0 + 3];

  const float* rp = pred + (base << 8) + c0;

  auto scat = [&](float* s, const float4& v) {
    s[t0] = __logf(v.x);
    s[t1] = __logf(v.y);
    s[t2] = __logf(v.z);
    s[t3] = __logf(v.w);
  };

  float s0 = 0.f, s1 = 0.f, s2 = 0.f, s3 = 0.f;
  auto gath = [&](const float* ps, int m) {
    const int mx = m ^ l;
    s0 += ps[mx];
    s1 += ps[mx ^ 64];
    s2 += ps[mx ^ 128];
    s3 += ps[mx ^ 192];
  };

  float4 vA = *reinterpret_cast<const float4*>(rp + 0 * NGUESS);
  float4 vB = *reinterpret_cast<const float4*>(rp + 1 * NGUESS);
  float4 nA = *reinterpret_cast<const float4*>(rp + 2 * NGUESS);
  float4 nB = *reinterpret_cast<const float4*>(rp + 3 * NGUESS);
  int pmA = meta[base + 0];
  int pmB = meta[base + 1];

  scat(prow[w][0], vA);
  scat(prow[w][1], vB);

#pragma unroll
  for (int p = 1; p < 12; ++p) {
    vA = nA; vB = nB;
    const int rA = (2 * p + 2 <= 24) ? (2 * p + 2) : 24;
    const int rB = (2 * p + 3 <= 24) ? (2 * p + 3) : 24;
    nA = *reinterpret_cast<const float4*>(rp + (size_t)rA * NGUESS);
    nB = *reinterpret_cast<const float4*>(rp + (size_t)rB * NGUESS);
    const int mA = meta[base + 2 * p];
    const int mB = meta[base + 2 * p + 1];

    float* sA = prow[w][2 * (p & 1)];
    scat(sA, vA);
    scat(sA + NGUESS, vB);

    const float* gA = prow[w][2 * ((p & 1) ^ 1)];
    gath(gA, pmA);
    gath(gA + NGUESS, pmB);

    pmA = mA; pmB = mB;
  }

  scat(prow[w][0], nA);
  gath(prow[w][2], pmA);
  gath(prow[w][3], pmB);
  gath(prow[w][0], meta[base + 24]);

  red[w][l]       = s0;
  red[w][l + 64]  = s1;
  red[w][l + 128] = s2;
  red[w][l + 192] = s3;
  __syncthreads();
  cs[((size_t)blockIdx.x) * NGUESS + tid] =
      red[0][tid] + red[1][tid] + red[2][tid] + red[3][tid];
}

// K2a': block-scan per COLUMN, widened to 512 threads (2 chunks/thread,
// 9-step Hillis-Steele) — halves the per-thread serial load chain vs r12's
// 4-chunk version and doubles waves/CU for this latency-bound kernel.
__global__ __launch_bounds__(512) void k_scan(const float* __restrict__ cs,
                                              double* __restrict__ S,
                                              int nc) {
  const int g = blockIdx.x;
  const int t = threadIdx.x;
  const int r0 = t << 1;

  const double x0 = (r0 + 0 < nc) ? (double)cs[(size_t)(r0 + 0) * NGUESS + g] : 0.0;
  const double x1 = (r0 + 1 < nc) ? (double)cs[(size_t)(r0 + 1) * NGUESS + g] : 0.0;
  const double p0 = x0;
  const double p1 = x0 + x1;

  __shared__ double sc[512];
  sc[t] = p1;
  __syncthreads();
#pragma unroll
  for (int off = 1; off < 512; off <<= 1) {
    const double v = sc[t];
    const double u = (t >= off) ? sc[t - off] : 0.0;
    __syncthreads();
    sc[t] = v + u;
    __syncthreads();
  }
  const double E = (t > 0) ? sc[t - 1] : 0.0;  // exclusive prefix of this thread

  if (r0 + 0 < nc) S[(size_t)(r0 + 0) * NGUESS + g] = E + p0;
  if (r0 + 1 < nc) S[(size_t)(r0 + 1) * NGUESS + g] = E + p1;
}

// K2b': one block per chunk; ONE coalesced load + ballot + popcount.
__global__ __launch_bounds__(256) void k_ranks3(const double* __restrict__ S,
                                                const int* __restrict__ ckp,
                                                int* __restrict__ outRanks,
                                                int* __restrict__ outX) {
  const int c = blockIdx.x;
  const int g = threadIdx.x;
  const double s = S[(size_t)c * NGUESS + g];

  __shared__ double keysh;
  __shared__ int cnt;
  if (g == *ckp) keysh = s;
  if (g == 0) cnt = 0;
  __syncthreads();
  const unsigned long long mb = __ballot(s > keysh);
  if ((g & 63) == 0) atomicAdd(&cnt, (int)__popcll(mb));
  __syncthreads();
  if (g == 0) {
    outRanks[c] = cnt;
    outX[c] = (c + 1) * 100;
  }
}

extern "C" void kernel_launch(void* const* d_in, const int* in_sizes, int n_in,
                              void* d_out, int out_size, void* d_ws, size_t ws_size,
                              hipStream_t stream) {
  const float* pred = (const float*)d_in[0];
  const int* meta   = (const int*)d_in[1];
  // d_in[2] = guess_range (256), d_in[3] = correct_key (34), d_in[4] = step (100)
  const int* ckp    = (const int*)d_in[3];

  const int N = in_sizes[1];             // 100000
  const int num_chunks = N / 100;        // 1000

  double* S  = (double*)d_ws;                                   // [1000][256] f64 (8B-aligned at base)
  float*  cs = (float*)((char*)d_ws +
                        (size_t)num_chunks * NGUESS * sizeof(double)); // [1000][256] f32

  int* outRanks = (int*)d_out;           // ranks[0..nc)
  int* outX     = outRanks + num_chunks; // x_rank[nc..2nc)

  k_chunksums<<<num_chunks, 256, 0, stream>>>(pred, meta, cs);
  k_scan     <<<NGUESS,     512, 0, stream>>>(cs, S, num_chunks);
  k_ranks3   <<<num_chunks, 256, 0, stream>>>(S, ckp, outRanks, outX);
}